// Round 13
// baseline (68.618 us; speedup 1.0000x reference)
//
#include <hip/hip_runtime.h>
#include <stdint.h>

#define B_ROWS 128
#define V_COLS 128000
#define BPR 16                       // blocks per row
#define SLICE (V_COLS / BPR)         // 8000 floats
#define N4 (SLICE / 4)               // 2000 float4
#define NTHR 256
#define CAP 2048

typedef uint32_t u32x4 __attribute__((ext_vector_type(4)));

// monotone transform on raw float bits: larger float <-> larger uint
__device__ __forceinline__ uint32_t f2u_bits(uint32_t x) {
    return (x & 0x80000000u) ? ~x : (x | 0x80000000u);
}
__device__ __forceinline__ float u2f(uint32_t u) {
    uint32_t x = (u & 0x80000000u) ? (u & 0x7FFFFFFFu) : ~u;
    return __uint_as_float(x);
}

// pair compare, descending order, ties: larger idx first
__device__ __forceinline__ bool pair_gt(uint32_t au, uint32_t ai, uint32_t bu, uint32_t bi) {
    return (au > bu) || (au == bu && ai > bi);
}

// ---- merge two descending sorted 64-runs (1 elem/lane): keep top-64, sorted desc ----
__device__ __forceinline__ void merge64(uint32_t& au, uint32_t& ai,
                                        uint32_t bu, uint32_t bi, int lane) {
    uint32_t ou = (uint32_t)__shfl_xor((int)bu, 63, 64);
    uint32_t oi = (uint32_t)__shfl_xor((int)bi, 63, 64);
    if (!pair_gt(au, ai, ou, oi)) { au = ou; ai = oi; }
    #pragma unroll
    for (int j = 32; j >= 1; j >>= 1) {
        uint32_t cu = (uint32_t)__shfl_xor((int)au, j, 64);
        uint32_t ci = (uint32_t)__shfl_xor((int)ai, j, 64);
        bool sg = pair_gt(au, ai, cu, ci);
        bool keep = ((lane & j) == 0) ? sg : !sg;
        if (!keep) { au = cu; ai = ci; }
    }
}

// ---- in-register wave bitonic sort of 64 (u,idx) pairs, descending ----
__device__ __forceinline__ void wave_sort64(uint32_t& u, uint32_t& i, int lane) {
    #pragma unroll
    for (int ksz = 2; ksz <= 64; ksz <<= 1) {
        #pragma unroll
        for (int j = ksz >> 1; j > 0; j >>= 1) {
            uint32_t ou = (uint32_t)__shfl_xor((int)u, j, 64);
            uint32_t oi = (uint32_t)__shfl_xor((int)i, j, 64);
            bool asc   = (lane & ksz) == 0;
            bool lower = (lane & j) == 0;
            bool sg = pair_gt(u, i, ou, oi);
            bool keep = (asc == lower) ? sg : !sg;
            if (!keep) { u = ou; i = oi; }
        }
    }
}

// ---- LDS bitonic (fallback only), descending, ties: larger idx first ----
__device__ __forceinline__ void lds_bitonic_desc(uint32_t* su, uint32_t* si, int NP) {
    const int tid = threadIdx.x;
    for (int ksz = 2; ksz <= NP; ksz <<= 1) {
        for (int j = ksz >> 1; j > 0; j >>= 1) {
            __syncthreads();
            for (int i = tid; i < NP; i += NTHR) {
                int ixj = i ^ j;
                if (ixj > i) {
                    uint32_t ua = su[i], ub = su[ixj];
                    uint32_t ia = si[i], ib = si[ixj];
                    bool a_lt = (ua < ub) || (ua == ub && ia < ib);
                    if (((i & ksz) == 0) ? a_lt : !a_lt) {
                        su[i] = ub; su[ixj] = ua;
                        si[i] = ib; si[ixj] = ia;
                    }
                }
            }
        }
    }
    __syncthreads();
}

// ---- finalize: merge 16 runs + sample. __noinline__ so its code is OUTSIDE the
// main kernel's scheduling/regalloc scope: r5/r6/r7/r12 showed that inlining this
// tail flips the whole kernel into a 28-32 VGPR serialized-load schedule (5x slower
// load phase). As a separate call, the main body compiles like the proven 52-VGPR
// standalone K1. ----
__device__ __attribute__((noinline)) void finalize_row(
    const uint2* __restrict__ br, const int* __restrict__ kk,
    const float* __restrict__ pp, const float* __restrict__ noise,
    int* __restrict__ out, uint32_t* s_u, uint32_t* s_i, int row)
{
    const int tid = threadIdx.x;
    const int lane = tid & 63;
    const int wv   = tid >> 6;

    uint2 r0 = br[(wv * 4 + 0) * 64 + lane];
    uint2 r1 = br[(wv * 4 + 1) * 64 + lane];
    uint2 r2 = br[(wv * 4 + 2) * 64 + lane];
    uint2 r3 = br[(wv * 4 + 3) * 64 + lane];
    uint32_t a0u = r0.x, a0i = r0.y;
    uint32_t a1u = r1.x, a1i = r1.y;
    uint32_t a2u = r2.x, a2i = r2.y;
    uint32_t a3u = r3.x, a3i = r3.y;
    merge64(a0u, a0i, a1u, a1i, lane);
    merge64(a2u, a2i, a3u, a3i, lane);
    merge64(a0u, a0i, a2u, a2i, lane);
    s_u[wv * 64 + lane] = a0u;
    s_i[wv * 64 + lane] = a0i;
    __syncthreads();

    if (wv == 0) {
        uint32_t b1u = s_u[64 + lane];  uint32_t b1i = s_i[64 + lane];
        uint32_t b2u = s_u[128 + lane]; uint32_t b2i = s_i[128 + lane];
        uint32_t b3u = s_u[192 + lane]; uint32_t b3i = s_i[192 + lane];
        merge64(a0u, a0i, b1u, b1i, lane);
        merge64(b2u, b2i, b3u, b3i, lane);
        merge64(a0u, a0i, b2u, b2i, lane);
        // lane j now holds the (j+1)-th largest logit of the row, exact order

        float v2 = u2f(a0u);
        uint32_t tok = a0i;
        int k = kk[row];
        if (k > 64) k = 64;                    // safety; setup guarantees k<=63
        float p = pp[row];

        // top-k: threshold = k-th largest; keep v >= thr (value-domain, ties kept)
        float thrv = __shfl(v2, k - 1, 64);
        bool kept = v2 >= thrv;
        float m = __shfl(v2, 0, 64);           // row max
        float e = kept ? expf(v2 - m) : 0.0f;

        // softmax denom over kept
        float denom = e;
        #pragma unroll
        for (int off = 1; off < 64; off <<= 1) denom += __shfl_xor(denom, off, 64);
        float prob = e / denom;

        // ascending-inclusive cumsum == suffix sum over descending lanes
        float cums = prob;
        #pragma unroll
        for (int off = 1; off < 64; off <<= 1) {
            float o = __shfl_down(cums, off, 64);
            cums += (lane + off < 64) ? o : 0.0f;
        }
        // top-p: mask cumsum <= 1-p, but always keep the max (lane 0)
        bool masked = (cums <= 1.0f - p) && (lane != 0);
        bool surv = kept && !masked;

        // renormalize over survivors
        float e2 = surv ? e : 0.0f;
        float denom2 = e2;
        #pragma unroll
        for (int off = 1; off < 64; off <<= 1) denom2 += __shfl_xor(denom2, off, 64);

        float score = -1.0f;
        uint32_t bidx = 0xFFFFFFFFu;
        if (surv) {
            float nz = noise[(size_t)row * V_COLS + tok];
            score = (e / denom2) / nz;         // probs / Exp(1) noise
            bidx = tok;
        }
        // argmax, tie -> smaller token index (matches jnp first-occurrence)
        #pragma unroll
        for (int off = 1; off < 64; off <<= 1) {
            float os = __shfl_xor(score, off, 64);
            uint32_t oi = __shfl_xor(bidx, off, 64);
            if (os > score || (os == score && oi < bidx)) { score = os; bidx = oi; }
        }
        if (lane == 0) out[row] = (int)bidx;
    }
}

__global__ __launch_bounds__(NTHR) void fused_topk_sample_kernel(
    const float* __restrict__ logits, const int* __restrict__ kk,
    const float* __restrict__ pp, const float* __restrict__ noise,
    uint2* __restrict__ ws_run, unsigned int* __restrict__ counters,
    int* __restrict__ out)
{
    __shared__ uint32_t s_u[CAP];
    __shared__ uint32_t s_i[CAP];
    __shared__ uint32_t s_T[4];
    __shared__ int s_cnt;
    __shared__ int s_last;

    const int blk = blockIdx.x;
    const int row = blk >> 4;
    const int q   = blk & 15;
    const int tid = threadIdx.x;
    const int lane = tid & 63;
    const int wv   = tid >> 6;

    if (tid == 0) s_cnt = 0;

    const u32x4* src = (const u32x4*)(logits + (size_t)row * V_COLS + (size_t)q * SLICE);

    // ---- 8 independent dwordx4 NON-TEMPORAL loads (r11's proven 52-VGPR body) ----
    u32x4 g[8];
    #pragma unroll
    for (int j = 0; j < 8; ++j) {
        int i4 = j * NTHR + tid;
        i4 = (i4 < N4) ? i4 : (N4 - 1);      // branch-free clamp; only j==7 can clamp
        g[j] = __builtin_nontemporal_load(&src[i4]);
    }
    // ---- convert in place to monotone uints ----
    #pragma unroll
    for (int j = 0; j < 8; ++j) {
        g[j].x = f2u_bits(g[j].x); g[j].y = f2u_bits(g[j].y);
        g[j].z = f2u_bits(g[j].z); g[j].w = f2u_bits(g[j].w);
    }
    if (7 * NTHR + tid >= N4) { g[7].x = 0u; g[7].y = 0u; g[7].z = 0u; g[7].w = 0u; }

    // ---- per-thread max ----
    uint32_t mx = 0u;
    #pragma unroll
    for (int j = 0; j < 8; ++j) {
        uint32_t a = g[j].x > g[j].y ? g[j].x : g[j].y;
        uint32_t b = g[j].z > g[j].w ? g[j].z : g[j].w;
        a = a > b ? a : b;
        mx = mx > a ? mx : a;
    }

    // ---- per-wave ascending register sort of the 64 thread-maxes ----
    uint32_t v = mx;
    #pragma unroll
    for (int ksz = 2; ksz <= 64; ksz <<= 1) {
        #pragma unroll
        for (int j = ksz >> 1; j > 0; j >>= 1) {
            uint32_t o = (uint32_t)__shfl_xor((int)v, j, 64);
            bool asc   = (lane & ksz) == 0;
            bool lower = (lane & j) == 0;
            uint32_t mn = (v < o) ? v : o;
            uint32_t mh = (v < o) ? o : v;
            v = (asc == lower) ? mn : mh;
        }
    }
    // lane 48 = 16th-largest thread-max of this wave -> >=16 slice elems >= Tw
    uint32_t Tw = (uint32_t)__shfl((int)v, 48, 64);
    if (lane == 0) s_T[wv] = Tw;
    __syncthreads();
    uint32_t T0 = s_T[0] < s_T[1] ? s_T[0] : s_T[1];
    uint32_t T1 = s_T[2] < s_T[3] ? s_T[2] : s_T[3];
    uint32_t T = T0 < T1 ? T0 : T1;   // >= 64 slice elements are >= T

    // ---- append candidates (expected ~90-250 per block) ----
    #pragma unroll
    for (int j = 0; j < 8; ++j) {
        const int base = q * SLICE + (j * NTHR + tid) * 4;
        uint32_t uu0 = g[j].x, uu1 = g[j].y, uu2 = g[j].z, uu3 = g[j].w;
        if (uu0 >= T && uu0 != 0u) { int p = atomicAdd(&s_cnt, 1); if (p < CAP) { s_u[p] = uu0; s_i[p] = (uint32_t)(base + 0); } }
        if (uu1 >= T && uu1 != 0u) { int p = atomicAdd(&s_cnt, 1); if (p < CAP) { s_u[p] = uu1; s_i[p] = (uint32_t)(base + 1); } }
        if (uu2 >= T && uu2 != 0u) { int p = atomicAdd(&s_cnt, 1); if (p < CAP) { s_u[p] = uu2; s_i[p] = (uint32_t)(base + 2); } }
        if (uu3 >= T && uu3 != 0u) { int p = atomicAdd(&s_cnt, 1); if (p < CAP) { s_u[p] = uu3; s_i[p] = (uint32_t)(base + 3); } }
    }
    __syncthreads();
    int cnt = s_cnt; if (cnt > CAP) cnt = CAP;

    if (cnt <= 256) {
        // fast path: pad to 256, per-wave register sort, wave-0 tournament merge
        for (int i = cnt + tid; i < 256; i += NTHR) { s_u[i] = 0u; s_i[i] = 0xFFFFFFFFu; }
        __syncthreads();
        uint32_t cu = s_u[wv * 64 + lane];
        uint32_t ci = s_i[wv * 64 + lane];
        wave_sort64(cu, ci, lane);
        s_u[wv * 64 + lane] = cu;
        s_i[wv * 64 + lane] = ci;
        __syncthreads();
        if (wv == 0) {
            uint32_t b1u = s_u[64 + lane];  uint32_t b1i = s_i[64 + lane];
            uint32_t b2u = s_u[128 + lane]; uint32_t b2i = s_i[128 + lane];
            uint32_t b3u = s_u[192 + lane]; uint32_t b3i = s_i[192 + lane];
            merge64(cu, ci, b1u, b1i, lane);
            merge64(b2u, b2i, b3u, b3i, lane);
            merge64(cu, ci, b2u, b2i, lane);
            ws_run[blk * 64 + lane] = make_uint2(cu, ci);
        }
    } else {
        // fallback (pathological data only)
        int NP = 256; while (NP < cnt) NP <<= 1;
        for (int i = cnt + tid; i < NP; i += NTHR) { s_u[i] = 0u; s_i[i] = 0xFFFFFFFFu; }
        lds_bitonic_desc(s_u, s_i, NP);
        if (tid < 64) ws_run[blk * 64 + tid] = make_uint2(s_u[tid], s_i[tid]);
    }
    __syncthreads();   // all ws stores of this block issued

    // ---- last-block-of-row detection (poison-tolerant, self-resetting) ----
    if (tid == 0) {
        __threadfence();                                   // release our ws writes
        unsigned int raw = atomicAdd(&counters[row], 1u);  // device-scope by default
        unsigned int eff = (raw >= 0xAAAAAAAAu) ? (raw - 0xAAAAAAAAu) : raw;
        s_last = (eff == 15u) ? 1 : 0;
        if (s_last) {
            counters[row] = 0u;       // reset for next replay (all adds done)
            __threadfence();          // acquire side: see other XCDs' ws writes
        }
    }
    __syncthreads();
    if (!s_last) return;

    finalize_row(ws_run + (size_t)row * (BPR * 64), kk, pp, noise, out, s_u, s_i, row);
}

extern "C" void kernel_launch(void* const* d_in, const int* in_sizes, int n_in,
                              void* d_out, int out_size, void* d_ws, size_t ws_size,
                              hipStream_t stream) {
    const float* logits = (const float*)d_in[0];
    const int* kk       = (const int*)d_in[1];
    const float* pp     = (const float*)d_in[2];
    const float* noise  = (const float*)d_in[3];
    int* out            = (int*)d_out;

    uint2*        ws_run = (uint2*)d_ws;                                 // 2048*64 uint2 = 1 MiB
    unsigned int* cnt    = (unsigned int*)d_ws + 2 * (size_t)B_ROWS * BPR * 64; // 128 u32

    fused_topk_sample_kernel<<<B_ROWS * BPR, NTHR, 0, stream>>>(
        logits, kk, pp, noise, ws_run, cnt, out);
}

// Round 14
// 25.831 us; speedup vs baseline: 2.6565x; 2.6565x over previous
//
#include <hip/hip_runtime.h>
#include <stdint.h>

#define B_ROWS 128
#define V_COLS 128000
#define BPR 16                       // blocks per row
#define SLICE (V_COLS / BPR)         // 8000 floats
#define N4 (SLICE / 4)               // 2000 float4
#define NTHR 256
#define CAP 2048

typedef uint32_t u32x4 __attribute__((ext_vector_type(4)));

// monotone transform on raw float bits: larger float <-> larger uint
__device__ __forceinline__ uint32_t f2u_bits(uint32_t x) {
    return (x & 0x80000000u) ? ~x : (x | 0x80000000u);
}
__device__ __forceinline__ float u2f(uint32_t u) {
    uint32_t x = (u & 0x80000000u) ? (u & 0x7FFFFFFFu) : ~u;
    return __uint_as_float(x);
}

// pair compare, descending order, ties: larger idx first
__device__ __forceinline__ bool pair_gt(uint32_t au, uint32_t ai, uint32_t bu, uint32_t bi) {
    return (au > bu) || (au == bu && ai > bi);
}

// ---- merge two descending sorted 64-runs (1 elem/lane): keep top-64, sorted desc ----
__device__ __forceinline__ void merge64(uint32_t& au, uint32_t& ai,
                                        uint32_t bu, uint32_t bi, int lane) {
    uint32_t ou = (uint32_t)__shfl_xor((int)bu, 63, 64);
    uint32_t oi = (uint32_t)__shfl_xor((int)bi, 63, 64);
    if (!pair_gt(au, ai, ou, oi)) { au = ou; ai = oi; }
    #pragma unroll
    for (int j = 32; j >= 1; j >>= 1) {
        uint32_t cu = (uint32_t)__shfl_xor((int)au, j, 64);
        uint32_t ci = (uint32_t)__shfl_xor((int)ai, j, 64);
        bool sg = pair_gt(au, ai, cu, ci);
        bool keep = ((lane & j) == 0) ? sg : !sg;
        if (!keep) { au = cu; ai = ci; }
    }
}

// ---- in-register wave bitonic sort of 64 (u,idx) pairs, descending ----
__device__ __forceinline__ void wave_sort64(uint32_t& u, uint32_t& i, int lane) {
    #pragma unroll
    for (int ksz = 2; ksz <= 64; ksz <<= 1) {
        #pragma unroll
        for (int j = ksz >> 1; j > 0; j >>= 1) {
            uint32_t ou = (uint32_t)__shfl_xor((int)u, j, 64);
            uint32_t oi = (uint32_t)__shfl_xor((int)i, j, 64);
            bool asc   = (lane & ksz) == 0;
            bool lower = (lane & j) == 0;
            bool sg = pair_gt(u, i, ou, oi);
            bool keep = (asc == lower) ? sg : !sg;
            if (!keep) { u = ou; i = oi; }
        }
    }
}

// ---- LDS bitonic (fallback only), descending, ties: larger idx first ----
__device__ __forceinline__ void lds_bitonic_desc(uint32_t* su, uint32_t* si, int NP) {
    const int tid = threadIdx.x;
    for (int ksz = 2; ksz <= NP; ksz <<= 1) {
        for (int j = ksz >> 1; j > 0; j >>= 1) {
            __syncthreads();
            for (int i = tid; i < NP; i += NTHR) {
                int ixj = i ^ j;
                if (ixj > i) {
                    uint32_t ua = su[i], ub = su[ixj];
                    uint32_t ia = si[i], ib = si[ixj];
                    bool a_lt = (ua < ub) || (ua == ub && ia < ib);
                    if (((i & ksz) == 0) ? a_lt : !a_lt) {
                        su[i] = ub; su[ixj] = ua;
                        si[i] = ib; si[ixj] = ia;
                    }
                }
            }
        }
    }
    __syncthreads();
}

// K1: per (row, 1/16-slice) block: exact top-64 (sorted desc) of the slice.
__global__ __launch_bounds__(NTHR) void topk_slice_kernel(
    const float* __restrict__ logits, uint2* __restrict__ out_run)
{
    __shared__ uint32_t s_u[CAP];
    __shared__ uint32_t s_i[CAP];
    __shared__ uint32_t s_T[4];
    __shared__ int s_cnt;

    const int blk = blockIdx.x;
    const int row = blk >> 4;
    const int q   = blk & 15;
    const int tid = threadIdx.x;
    const int lane = tid & 63;
    const int wv   = tid >> 6;

    if (tid == 0) s_cnt = 0;

    const u32x4* src = (const u32x4*)(logits + (size_t)row * V_COLS + (size_t)q * SLICE);

    // ---- 8 independent dwordx4 NON-TEMPORAL loads (no L2/L3 allocation: data is
    // read exactly once; nt keeps the return path from thrashing the caches) ----
    u32x4 g[8];
    #pragma unroll
    for (int j = 0; j < 8; ++j) {
        int i4 = j * NTHR + tid;
        i4 = (i4 < N4) ? i4 : (N4 - 1);      // branch-free clamp; only j==7 can clamp
        g[j] = __builtin_nontemporal_load(&src[i4]);
    }
    // ---- convert in place to monotone uints ----
    #pragma unroll
    for (int j = 0; j < 8; ++j) {
        g[j].x = f2u_bits(g[j].x); g[j].y = f2u_bits(g[j].y);
        g[j].z = f2u_bits(g[j].z); g[j].w = f2u_bits(g[j].w);
    }
    if (7 * NTHR + tid >= N4) { g[7].x = 0u; g[7].y = 0u; g[7].z = 0u; g[7].w = 0u; }

    // ---- per-thread max ----
    uint32_t mx = 0u;
    #pragma unroll
    for (int j = 0; j < 8; ++j) {
        uint32_t a = g[j].x > g[j].y ? g[j].x : g[j].y;
        uint32_t b = g[j].z > g[j].w ? g[j].z : g[j].w;
        a = a > b ? a : b;
        mx = mx > a ? mx : a;
    }

    // ---- per-wave ascending register sort of the 64 thread-maxes ----
    uint32_t v = mx;
    #pragma unroll
    for (int ksz = 2; ksz <= 64; ksz <<= 1) {
        #pragma unroll
        for (int j = ksz >> 1; j > 0; j >>= 1) {
            uint32_t o = (uint32_t)__shfl_xor((int)v, j, 64);
            bool asc   = (lane & ksz) == 0;
            bool lower = (lane & j) == 0;
            uint32_t mn = (v < o) ? v : o;
            uint32_t mh = (v < o) ? o : v;
            v = (asc == lower) ? mn : mh;
        }
    }
    // lane 48 = 16th-largest thread-max of this wave -> >=16 slice elems >= Tw
    uint32_t Tw = (uint32_t)__shfl((int)v, 48, 64);
    if (lane == 0) s_T[wv] = Tw;
    __syncthreads();
    uint32_t T0 = s_T[0] < s_T[1] ? s_T[0] : s_T[1];
    uint32_t T1 = s_T[2] < s_T[3] ? s_T[2] : s_T[3];
    uint32_t T = T0 < T1 ? T0 : T1;   // >= 64 slice elements are >= T

    // ---- append candidates (expected ~90-250 per block) ----
    #pragma unroll
    for (int j = 0; j < 8; ++j) {
        const int base = q * SLICE + (j * NTHR + tid) * 4;
        uint32_t uu0 = g[j].x, uu1 = g[j].y, uu2 = g[j].z, uu3 = g[j].w;
        if (uu0 >= T && uu0 != 0u) { int p = atomicAdd(&s_cnt, 1); if (p < CAP) { s_u[p] = uu0; s_i[p] = (uint32_t)(base + 0); } }
        if (uu1 >= T && uu1 != 0u) { int p = atomicAdd(&s_cnt, 1); if (p < CAP) { s_u[p] = uu1; s_i[p] = (uint32_t)(base + 1); } }
        if (uu2 >= T && uu2 != 0u) { int p = atomicAdd(&s_cnt, 1); if (p < CAP) { s_u[p] = uu2; s_i[p] = (uint32_t)(base + 2); } }
        if (uu3 >= T && uu3 != 0u) { int p = atomicAdd(&s_cnt, 1); if (p < CAP) { s_u[p] = uu3; s_i[p] = (uint32_t)(base + 3); } }
    }
    __syncthreads();
    int cnt = s_cnt; if (cnt > CAP) cnt = CAP;

    if (cnt <= 256) {
        // fast path: pad to 256, per-wave register sort, wave-0 tournament merge
        for (int i = cnt + tid; i < 256; i += NTHR) { s_u[i] = 0u; s_i[i] = 0xFFFFFFFFu; }
        __syncthreads();
        uint32_t cu = s_u[wv * 64 + lane];
        uint32_t ci = s_i[wv * 64 + lane];
        wave_sort64(cu, ci, lane);
        s_u[wv * 64 + lane] = cu;
        s_i[wv * 64 + lane] = ci;
        __syncthreads();
        if (wv == 0) {
            uint32_t b1u = s_u[64 + lane];  uint32_t b1i = s_i[64 + lane];
            uint32_t b2u = s_u[128 + lane]; uint32_t b2i = s_i[128 + lane];
            uint32_t b3u = s_u[192 + lane]; uint32_t b3i = s_i[192 + lane];
            merge64(cu, ci, b1u, b1i, lane);
            merge64(b2u, b2i, b3u, b3i, lane);
            merge64(cu, ci, b2u, b2i, lane);
            out_run[blk * 64 + lane] = make_uint2(cu, ci);
        }
    } else {
        // fallback (pathological data only)
        int NP = 256; while (NP < cnt) NP <<= 1;
        for (int i = cnt + tid; i < NP; i += NTHR) { s_u[i] = 0u; s_i[i] = 0xFFFFFFFFu; }
        lds_bitonic_desc(s_u, s_i, NP);
        if (tid < 64) out_run[blk * 64 + tid] = make_uint2(s_u[tid], s_i[tid]);
    }
}

// K2: one block per row: register tournament-merge 16 sorted runs, then filter + sample.
__global__ __launch_bounds__(NTHR) void sample_kernel(
    const uint2* __restrict__ runs,
    const int* __restrict__ kk, const float* __restrict__ pp,
    const float* __restrict__ noise, int* __restrict__ out)
{
    __shared__ uint32_t m_u[4 * 64];
    __shared__ uint32_t m_i[4 * 64];
    const int row = blockIdx.x;
    const int tid = threadIdx.x;
    const int lane = tid & 63;
    const int wv   = tid >> 6;

    const uint2* br = runs + (size_t)row * (BPR * 64);

    // wave wv merges its 4 sorted runs entirely in registers (3 merges)
    uint2 r0 = br[(wv * 4 + 0) * 64 + lane];
    uint2 r1 = br[(wv * 4 + 1) * 64 + lane];
    uint2 r2 = br[(wv * 4 + 2) * 64 + lane];
    uint2 r3 = br[(wv * 4 + 3) * 64 + lane];
    uint32_t a0u = r0.x, a0i = r0.y;
    uint32_t a1u = r1.x, a1i = r1.y;
    uint32_t a2u = r2.x, a2i = r2.y;
    uint32_t a3u = r3.x, a3i = r3.y;
    merge64(a0u, a0i, a1u, a1i, lane);
    merge64(a2u, a2i, a3u, a3i, lane);
    merge64(a0u, a0i, a2u, a2i, lane);
    m_u[wv * 64 + lane] = a0u;
    m_i[wv * 64 + lane] = a0i;
    __syncthreads();

    if (wv == 0) {
        uint32_t b1u = m_u[64 + lane];  uint32_t b1i = m_i[64 + lane];
        uint32_t b2u = m_u[128 + lane]; uint32_t b2i = m_i[128 + lane];
        uint32_t b3u = m_u[192 + lane]; uint32_t b3i = m_i[192 + lane];
        merge64(a0u, a0i, b1u, b1i, lane);
        merge64(b2u, b2i, b3u, b3i, lane);
        merge64(a0u, a0i, b2u, b2i, lane);
        // lane j now holds the (j+1)-th largest logit of the row, exact order

        float v2 = u2f(a0u);
        uint32_t tok = a0i;
        int k = kk[row];
        if (k > 64) k = 64;                    // safety; setup guarantees k<=63
        float p = pp[row];

        // top-k: threshold = k-th largest; keep v >= thr (value-domain, ties kept)
        float thrv = __shfl(v2, k - 1, 64);
        bool kept = v2 >= thrv;
        float m = __shfl(v2, 0, 64);           // row max
        float e = kept ? expf(v2 - m) : 0.0f;

        // softmax denom over kept
        float denom = e;
        #pragma unroll
        for (int off = 1; off < 64; off <<= 1) denom += __shfl_xor(denom, off, 64);
        float prob = e / denom;

        // ascending-inclusive cumsum == suffix sum over descending lanes
        float cums = prob;
        #pragma unroll
        for (int off = 1; off < 64; off <<= 1) {
            float o = __shfl_down(cums, off, 64);
            cums += (lane + off < 64) ? o : 0.0f;
        }
        // top-p: mask cumsum <= 1-p, but always keep the max (lane 0)
        bool masked = (cums <= 1.0f - p) && (lane != 0);
        bool surv = kept && !masked;

        // renormalize over survivors
        float e2 = surv ? e : 0.0f;
        float denom2 = e2;
        #pragma unroll
        for (int off = 1; off < 64; off <<= 1) denom2 += __shfl_xor(denom2, off, 64);

        float score = -1.0f;
        uint32_t bidx = 0xFFFFFFFFu;
        if (surv) {
            float nz = noise[(size_t)row * V_COLS + tok];
            score = (e / denom2) / nz;         // probs / Exp(1) noise
            bidx = tok;
        }
        // argmax, tie -> smaller token index (matches jnp first-occurrence)
        #pragma unroll
        for (int off = 1; off < 64; off <<= 1) {
            float os = __shfl_xor(score, off, 64);
            uint32_t oi = __shfl_xor(bidx, off, 64);
            if (os > score || (os == score && oi < bidx)) { score = os; bidx = oi; }
        }
        if (lane == 0) out[row] = (int)bidx;
    }
}

extern "C" void kernel_launch(void* const* d_in, const int* in_sizes, int n_in,
                              void* d_out, int out_size, void* d_ws, size_t ws_size,
                              hipStream_t stream) {
    const float* logits = (const float*)d_in[0];
    const int* kk       = (const int*)d_in[1];
    const float* pp     = (const float*)d_in[2];
    const float* noise  = (const float*)d_in[3];
    int* out            = (int*)d_out;

    uint2* ws_run = (uint2*)d_ws;    // 2048 * 64 uint2 = 1 MiB

    topk_slice_kernel<<<B_ROWS * BPR, NTHR, 0, stream>>>(logits, ws_run);
    sample_kernel<<<B_ROWS, NTHR, 0, stream>>>(ws_run, kk, pp, noise, out);
}